// Round 4
// baseline (328.331 us; speedup 1.0000x reference)
//
#include <hip/hip_runtime.h>

typedef unsigned short u16;
typedef __attribute__((ext_vector_type(8))) __bf16 bf16x8;
typedef __attribute__((ext_vector_type(4))) float f32x4;
typedef __attribute__((ext_vector_type(4))) u16 u16x4;
typedef __attribute__((ext_vector_type(8))) u16 u16x8;

constexpr int S = 2048;
constexpr int H = 2048;
constexpr int NH = 16;
constexpr int HD = 128;
constexpr int M = 4096;   // B*S
constexpr float SCALE = 0.08838834764831845f;  // 1/sqrt(128)

__device__ __forceinline__ u16 f2bf(float f) {
  union { float f; unsigned u; } v; v.f = f;
  unsigned r = v.u + 0x7fffu + ((v.u >> 16) & 1u);  // RNE
  return (u16)(r >> 16);
}
__device__ __forceinline__ float bf2f(u16 u) {
  union { unsigned u; float f; } v; v.u = ((unsigned)u) << 16;
  return v.f;
}
__device__ __forceinline__ unsigned cvt_pk_bf16(float lo, float hi) {
  unsigned r;
  asm("v_cvt_pk_bf16_f32 %0, %1, %2" : "=v"(r) : "v"(lo), "v"(hi));
  return r;
}
__device__ __forceinline__ f32x4 MFMA16(bf16x8 a, bf16x8 b, f32x4 c) {
  return __builtin_amdgcn_mfma_f32_16x16x32_bf16(a, b, c, 0, 0, 0);
}

// async global->LDS, 16 bytes per lane. LDS dest must be wave-uniform base + lane*16.
__device__ __forceinline__ void gld16(const u16* g, u16* l) {
  __builtin_amdgcn_global_load_lds(
      (const __attribute__((address_space(1))) void*)g,
      (__attribute__((address_space(3))) void*)l, 16, 0, 0);
}

#define SBAR  { __builtin_amdgcn_sched_barrier(0); __builtin_amdgcn_s_barrier(); __builtin_amdgcn_sched_barrier(0); }
#define LGKM0 { asm volatile("s_waitcnt lgkmcnt(0)" ::: "memory"); __builtin_amdgcn_sched_barrier(0); }
#define VM(N) { asm volatile("s_waitcnt vmcnt(" #N ")" ::: "memory"); }

// ---------------- fp32 -> bf16 cast (x) ----------------
__global__ __launch_bounds__(256) void cast_kernel(const float* __restrict__ in,
                                                   u16* __restrict__ out, int n) {
  int i = (blockIdx.x * 256 + threadIdx.x) * 4;
  if (i >= n) return;
  float4 v = *(const float4*)(in + i);
  u16x4 o;
  o[0] = f2bf(v.x); o[1] = f2bf(v.y); o[2] = f2bf(v.z); o[3] = f2bf(v.w);
  *(u16x4*)(out + i) = o;
}

// ---------------- 4 weight casts in one dispatch ----------------
__global__ __launch_bounds__(256) void cast4_kernel(const float* __restrict__ i0,
                                                    const float* __restrict__ i1,
                                                    const float* __restrict__ i2,
                                                    const float* __restrict__ i3,
                                                    u16* o0, u16* o1, u16* o2, u16* o3) {
  const float* in; u16* out;
  switch (blockIdx.y) {
    case 0: in = i0; out = o0; break;
    case 1: in = i1; out = o1; break;
    case 2: in = i2; out = o2; break;
    default: in = i3; out = o3; break;
  }
  int i = (blockIdx.x * 256 + threadIdx.x) * 4;
  float4 v = *(const float4*)(in + i);
  u16x4 o;
  o[0] = f2bf(v.x); o[1] = f2bf(v.y); o[2] = f2bf(v.z); o[3] = f2bf(v.w);
  *(u16x4*)(out + i) = o;
}

// ---------------- RoPE cos/sin table ----------------
__global__ __launch_bounds__(256) void rope_table_k(float* __restrict__ tab) {
  int i = blockIdx.x * 256 + threadIdx.x;
  if (i >= S * 64) return;
  int s = i >> 6, d = i & 63;
  float freq = expf(-(float)d * (9.210340371976184f / 64.f));  // 10000^(-d/64)
  float ang = (float)s * freq;
  tab[i * 2]     = cosf(ang);
  tab[i * 2 + 1] = sinf(ang);
}

// ---------------- RoPE apply to Q (pre-scaled) and K, one dispatch ----------------
__global__ __launch_bounds__(256) void rope_apply2_k(u16* __restrict__ Qb, u16* __restrict__ Kb,
                                                     const float* __restrict__ tab) {
  u16* X = blockIdx.y ? Kb : Qb;
  const float sc = blockIdx.y ? 1.f : SCALE;
  int i = blockIdx.x * 256 + threadIdx.x;
  int j0 = (i & 7) * 8;
  int h  = (i >> 3) & 15;
  int m  = i >> 7;
  int s  = m & (S - 1);
  u16* p = X + (size_t)m * H + h * HD;
  u16x8 lo = *(u16x8*)(p + j0);
  u16x8 hi = *(u16x8*)(p + 64 + j0);
  u16x8 nlo, nhi;
  const float* tb = tab + ((size_t)s * 64 + j0) * 2;
  #pragma unroll
  for (int j = 0; j < 8; ++j) {
    float c = tb[j * 2], sn = tb[j * 2 + 1];
    float xl = bf2f(lo[j]), xh = bf2f(hi[j]);
    nlo[j] = f2bf((xl * c - xh * sn) * sc);
    nhi[j] = f2bf((xh * c + xl * sn) * sc);
  }
  *(u16x8*)(p + j0) = nlo;
  *(u16x8*)(p + 64 + j0) = nhi;
}

// ================= 256x256 8-phase GEMM (T2+T3+T4+T5) =================
// C[m,n] = sum_k A[m,k]*W[n,k] + bias[n]; K=2048 (NT=32 K-tiles of 64, 16 iters).
// 8 waves (2M x 4N), per-wave 128x64 out. LDS 128 KiB: A/B x dbuf x [256][64] bf16.
// Chunk-XOR swizzle: LDS[row][j] holds source chunk j^(row&7) (staged via source
// swizzle, read via same involution) -> ds_read_b128 is 2-way = conflict-free.
// Per phase: ds_read subtile | stage 1 half-tile | barrier | lgkmcnt0 | 16 MFMA | barrier.
// Stage targets follow the death ledger; counted vmcnt(2) at phases 4/8 only.
__device__ __forceinline__ void gemm8_body(const u16* __restrict__ srcA,  // + brow*K
                                           const u16* __restrict__ srcB,  // + bcol*K
                                           const float* __restrict__ bias,
                                           void* __restrict__ Cout,
                                           int emode, int brow, int bcol,
                                           u16* AsL, u16* BsL) {
  const int t = threadIdx.x;            // 0..511
  const int w = t >> 6, l = t & 63;
  const int wr = w >> 2, wc = w & 3;
  const int lr = l & 15, lg = l >> 4;
  const int swz = lr & 7;

  f32x4 acc[8][4] = {};
  bf16x8 af[4][2], bA[2][2], bB[2][2];

  const int c0r = t >> 3,        c0j = t & 7;   // chunk t
  const int c1r = 64 + (t >> 3), c1j = t & 7;   // chunk 512+t

  // stage one half-tile (128 rows x 64 K) of SRC into {As|Bs}[BUF] half HALF, K-tile TILE
  #define STAGE(SRC, DSTB, BUF, HALF, TILE) do {                                   \
    u16* _d = (DSTB) + (BUF) * (256 * 64) + (HALF) * (128 * 64);                   \
    const u16* _s = (SRC) + ((size_t)((HALF) * 128)) * H + (TILE) * 64;            \
    gld16(_s + (size_t)c0r * H + ((c0j ^ (c0r & 7)) * 8), _d + t * 8);             \
    gld16(_s + (size_t)c1r * H + ((c1j ^ (c1r & 7)) * 8), _d + (512 + t) * 8);     \
  } while (0)

  #define LDA4(BUF, MB) do {                                                       \
    const u16* _b = AsL + (BUF) * (256 * 64) + (wr * 128 + lr) * 64;               \
    _Pragma("unroll") for (int i = 0; i < 4; ++i) {                                \
      af[i][0] = *(const bf16x8*)(_b + ((MB) + i) * (16 * 64) + ((lg ^ swz) * 8)); \
      af[i][1] = *(const bf16x8*)(_b + ((MB) + i) * (16 * 64) + (((4 + lg) ^ swz) * 8)); \
    } } while (0)

  #define LDB2(BUF, BF, NB) do {                                                   \
    const u16* _b = BsL + (BUF) * (256 * 64) + (wc * 64 + lr) * 64;                \
    _Pragma("unroll") for (int i = 0; i < 2; ++i) {                                \
      BF[i][0] = *(const bf16x8*)(_b + ((NB) + i) * (16 * 64) + ((lg ^ swz) * 8)); \
      BF[i][1] = *(const bf16x8*)(_b + ((NB) + i) * (16 * 64) + (((4 + lg) ^ swz) * 8)); \
    } } while (0)

  #define MM16(MB, BF, NB) do {                                                    \
    __builtin_amdgcn_s_setprio(1);                                                 \
    _Pragma("unroll") for (int i = 0; i < 4; ++i)                                  \
      _Pragma("unroll") for (int n = 0; n < 2; ++n) {                              \
        acc[(MB) + i][(NB) + n] = MFMA16(af[i][0], BF[n][0], acc[(MB) + i][(NB) + n]); \
        acc[(MB) + i][(NB) + n] = MFMA16(af[i][1], BF[n][1], acc[(MB) + i][(NB) + n]); \
      }                                                                            \
    __builtin_amdgcn_s_setprio(0);                                                 \
  } while (0)

  // ---- prologue: tile0 fully + B0(tile1); leave newest stage in flight ----
  STAGE(srcB, BsL, 0, 0, 0); STAGE(srcB, BsL, 0, 1, 0);
  STAGE(srcA, AsL, 0, 0, 0); STAGE(srcA, AsL, 0, 1, 0);
  STAGE(srcB, BsL, 1, 0, 1);
  VM(2);
  SBAR;

  for (int J = 0; J < 16; ++J) {
    const int u = 2 * J;
    const bool more = (J < 15);
    // ph1: Q0 of tile u (buf0)
    LDA4(0, 0); LDB2(0, bA, 0);
    STAGE(srcB, BsL, 1, 1, u + 1);
    SBAR; LGKM0;
    MM16(0, bA, 0);
    SBAR;
    // ph2: Q1
    LDA4(0, 4);
    STAGE(srcA, AsL, 1, 0, u + 1);
    SBAR; LGKM0;
    MM16(4, bA, 0);
    SBAR;
    // ph3: Q2
    LDB2(0, bB, 2);
    STAGE(srcA, AsL, 1, 1, u + 1);
    SBAR; LGKM0;
    MM16(4, bB, 2);
    SBAR;
    // ph4: Q3 (reload a0-3); gate tile u+1
    LDA4(0, 0);
    if (more) STAGE(srcB, BsL, 0, 0, u + 2);
    SBAR; LGKM0;
    MM16(0, bB, 2);
    if (more) { VM(2); } else { VM(0); }
    SBAR;
    // ph5: Q0 of tile u+1 (buf1)
    LDA4(1, 0); LDB2(1, bA, 0);
    if (more) STAGE(srcB, BsL, 0, 1, u + 2);
    SBAR; LGKM0;
    MM16(0, bA, 0);
    SBAR;
    // ph6: Q1
    LDA4(1, 4);
    if (more) STAGE(srcA, AsL, 0, 0, u + 2);
    SBAR; LGKM0;
    MM16(4, bA, 0);
    SBAR;
    // ph7: Q2
    LDB2(1, bB, 2);
    if (more) STAGE(srcA, AsL, 0, 1, u + 2);
    SBAR; LGKM0;
    MM16(4, bB, 2);
    SBAR;
    // ph8: Q3; gate tile u+2
    LDA4(1, 0);
    if (more) STAGE(srcB, BsL, 1, 0, u + 3);
    SBAR; LGKM0;
    MM16(0, bB, 2);
    if (more) VM(2);
    SBAR;
  }

  // ---- epilogue ----
  #pragma unroll
  for (int m = 0; m < 8; ++m) {
    const int row0 = brow + wr * 128 + m * 16 + lg * 4;
    #pragma unroll
    for (int n = 0; n < 4; ++n) {
      const int col = bcol + wc * 64 + n * 16 + lr;
      const float bv = bias[col];
      if (emode == 0) {
        float* C = (float*)Cout;
        #pragma unroll
        for (int r = 0; r < 4; ++r)
          C[(size_t)(row0 + r) * H + col] = acc[m][n][r] + bv;
      } else if (emode == 1) {
        u16* C = (u16*)Cout;
        #pragma unroll
        for (int r = 0; r < 4; ++r)
          C[(size_t)(row0 + r) * H + col] = f2bf(acc[m][n][r] + bv);
      } else {
        const int hh = col >> 7, d = col & 127;
        const int b = row0 >> 11, s0 = row0 & (S - 1);
        u16x4 pk;
        #pragma unroll
        for (int r = 0; r < 4; ++r) pk[r] = f2bf(acc[m][n][r] + bv);
        *(u16x4*)((u16*)Cout + ((size_t)((b * 16 + hh) * 128 + d)) * S + s0) = pk;
      }
    }
  }
  #undef STAGE
  #undef LDA4
  #undef LDB2
  #undef MM16
}

// QKV: grid 384 = 8(bx) x 16(by) x 3(z), XCD-swizzled (384%8==0 -> bijective)
__global__ __launch_bounds__(512, 2) void gemm8_qkv(const u16* __restrict__ xb,
                                                    const u16* __restrict__ wqb,
                                                    const u16* __restrict__ wkb,
                                                    const u16* __restrict__ wvb,
                                                    const float* __restrict__ bq,
                                                    const float* __restrict__ bk,
                                                    const float* __restrict__ bv,
                                                    u16* Qb, u16* Kb, u16* Vt) {
  __shared__ u16 AsL[2 * 256 * 64];
  __shared__ u16 BsL[2 * 256 * 64];
  const int id = blockIdx.x;
  const int lin = (id & 7) * 48 + (id >> 3);
  const int bz = lin >> 7, rem = lin & 127;
  const int bx = rem & 7, by = rem >> 3;
  const u16* Bw = (bz == 0) ? wqb : (bz == 1) ? wkb : wvb;
  const float* bias = (bz == 0) ? bq : (bz == 1) ? bk : bv;
  void* out = (bz == 0) ? (void*)Qb : (bz == 1) ? (void*)Kb : (void*)Vt;
  gemm8_body(xb + (size_t)(by * 256) * H, Bw + (size_t)(bx * 256) * H,
             bias, out, (bz == 2) ? 2 : 1, by * 256, bx * 256, AsL, BsL);
}

// out-proj: grid 128 = 8 x 16, fp32 output
__global__ __launch_bounds__(512, 2) void gemm8_out(const u16* __restrict__ A,
                                                    const u16* __restrict__ W,
                                                    const float* __restrict__ bias,
                                                    float* __restrict__ C) {
  __shared__ u16 AsL[2 * 256 * 64];
  __shared__ u16 BsL[2 * 256 * 64];
  const int id = blockIdx.x;
  const int lin = (id & 7) * 16 + (id >> 3);
  const int bx = lin & 7, by = lin >> 3;
  gemm8_body(A + (size_t)(by * 256) * H, W + (size_t)(bx * 256) * H,
             bias, (void*)C, 0, by * 256, bx * 256, AsL, BsL);
}

// ---------------- causal flash attention (unchanged from R3) ----------------
__global__ __launch_bounds__(256) void attn_fwd(const u16* __restrict__ Q,
                                                const u16* __restrict__ Kx,
                                                const u16* __restrict__ Vt,
                                                u16* __restrict__ O) {
  const int id = blockIdx.x;
  const int xcd = id & 7, slot = id >> 3;
  const int bh = (slot >> 4) * 8 + xcd;    // 0..31
  const int pid = slot & 15;               // 0..15
  const int b = bh >> 4, h = bh & 15;
  const int t = threadIdx.x, w = t >> 6, l = t & 63;
  const int lr = l & 15, lg = l >> 4;
  const int swz = lr & 7;

  __shared__ u16 Ks[2][64 * 128];
  __shared__ u16 Vs[2][128 * 64];
  __shared__ u16 P_lds[4][16 * 64];
  u16* pw = &P_lds[w][0];

  const u16* kbase = Kx + (size_t)(b * S) * H + h * HD;
  const u16* vbase = Vt + (size_t)bh * HD * S;

  auto stageK = [&](int bf, int k0) {
    #pragma unroll
    for (int it = 0; it < 4; ++it) {
      int c = it * 256 + t;
      int row = c >> 4, j = c & 15;
      gld16(kbase + (size_t)(k0 + row) * H + ((j ^ (row & 7)) * 8), &Ks[bf][0] + c * 8);
    }
  };
  auto stageV = [&](int bf, int k0) {
    #pragma unroll
    for (int it = 0; it < 4; ++it) {
      int c = it * 256 + t;
      int row = c >> 3, j = c & 7;
      gld16(vbase + (size_t)row * S + k0 + ((j ^ (row & 7)) * 8), &Vs[bf][0] + c * 8);
    }
  };

  int cur = 0;
  for (int qi = 0; qi < 2; ++qi) {
    const int qt = qi ? pid : (31 - pid);
    const int q0 = qt * 64 + w * 16;

    bf16x8 qa[4];
    const u16* qbase = Q + (size_t)(b * S + q0 + lr) * H + h * HD;
    #pragma unroll
    for (int ks = 0; ks < 4; ++ks)
      qa[ks] = *(const bf16x8*)(qbase + ks * 32 + lg * 8);

    f32x4 acc[8] = {};
    float mrun[4], lrun[4];
    #pragma unroll
    for (int r = 0; r < 4; ++r) { mrun[r] = -1e30f; lrun[r] = 0.f; }

    __syncthreads();
    stageK(cur, 0);
    stageV(cur, 0);
    __syncthreads();

    for (int kt = 0; kt <= qt; ++kt) {
      if (kt < qt) {
        stageK(cur ^ 1, (kt + 1) * 64);
        stageV(cur ^ 1, (kt + 1) * 64);
      }
      const u16* kl = &Ks[cur][0];
      const u16* vl = &Vs[cur][0];

      f32x4 sc[4] = {};
      __builtin_amdgcn_s_setprio(1);
      #pragma unroll
      for (int ks = 0; ks < 4; ++ks) {
        #pragma unroll
        for (int f = 0; f < 4; ++f) {
          bf16x8 kf = *(const bf16x8*)(kl + (f * 16 + lr) * 128 + (((ks * 4 + lg) ^ swz) * 8));
          sc[f] = __builtin_amdgcn_mfma_f32_16x16x32_bf16(qa[ks], kf, sc[f], 0, 0, 0);
        }
      }
      __builtin_amdgcn_s_setprio(0);
      const bool diag = (kt == qt);
      float p[4][4];
      #pragma unroll
      for (int f = 0; f < 4; ++f)
        #pragma unroll
        for (int r = 0; r < 4; ++r) {
          float v = sc[f][r];
          if (diag && (f * 16 + lr > w * 16 + lg * 4 + r)) v = -1e30f;
          p[f][r] = v;
        }
      float mx[4];
      #pragma unroll
      for (int r = 0; r < 4; ++r) {
        float m0 = fmaxf(fmaxf(p[0][r], p[1][r]), fmaxf(p[2][r], p[3][r]));
        m0 = fmaxf(m0, __shfl_xor(m0, 1));
        m0 = fmaxf(m0, __shfl_xor(m0, 2));
        m0 = fmaxf(m0, __shfl_xor(m0, 4));
        m0 = fmaxf(m0, __shfl_xor(m0, 8));
        mx[r] = m0;
      }
      bool grow = (mx[0] > mrun[0] + 8.f) || (mx[1] > mrun[1] + 8.f) ||
                  (mx[2] > mrun[2] + 8.f) || (mx[3] > mrun[3] + 8.f);
      if (__any(grow)) {
        float resc[4];
        #pragma unroll
        for (int r = 0; r < 4; ++r) {
          float mnew = fmaxf(mrun[r], mx[r]);
          resc[r] = __expf(mrun[r] - mnew);
          mrun[r] = mnew;
          lrun[r] *= resc[r];
        }
        #pragma unroll
        for (int fd = 0; fd < 8; ++fd) {
          f32x4 a = acc[fd];
          a[0] *= resc[0]; a[1] *= resc[1]; a[2] *= resc[2]; a[3] *= resc[3];
          acc[fd] = a;
        }
      }
      #pragma unroll
      for (int r = 0; r < 4; ++r) {
        float sum = 0.f;
        #pragma unroll
        for (int f = 0; f < 4; ++f) {
          float e = __expf(p[f][r] - mrun[r]);
          p[f][r] = e;
          sum += e;
        }
        sum += __shfl_xor(sum, 1);
        sum += __shfl_xor(sum, 2);
        sum += __shfl_xor(sum, 4);
        sum += __shfl_xor(sum, 8);
        lrun[r] += sum;
      }
      {
        const int r0 = lg * 4;
        #pragma unroll
        for (int f = 0; f < 4; ++f) {
          const int col = f * 16 + lr;
          unsigned w01 = cvt_pk_bf16(p[f][0], p[f][1]);
          unsigned w23 = cvt_pk_bf16(p[f][2], p[f][3]);
          pw[(r0 + 0) * 64 + (col ^ (((r0 + 0) & 7) << 3))] = (u16)(w01 & 0xffffu);
          pw[(r0 + 1) * 64 + (col ^ (((r0 + 1) & 7) << 3))] = (u16)(w01 >> 16);
          pw[(r0 + 2) * 64 + (col ^ (((r0 + 2) & 7) << 3))] = (u16)(w23 & 0xffffu);
          pw[(r0 + 3) * 64 + (col ^ (((r0 + 3) & 7) << 3))] = (u16)(w23 >> 16);
        }
      }
      __builtin_amdgcn_s_setprio(1);
      #pragma unroll
      for (int ks = 0; ks < 2; ++ks) {
        int col0 = ks * 32 + lg * 8;
        bf16x8 pa = *(const bf16x8*)(pw + lr * 64 + (col0 ^ (swz << 3)));
        #pragma unroll
        for (int fd = 0; fd < 8; ++fd) {
          bf16x8 vb = *(const bf16x8*)(vl + (fd * 16 + lr) * 64 + (((ks * 4 + lg) ^ swz) * 8));
          acc[fd] = __builtin_amdgcn_mfma_f32_16x16x32_bf16(pa, vb, acc[fd], 0, 0, 0);
        }
      }
      __builtin_amdgcn_s_setprio(0);
      __syncthreads();
      cur ^= 1;
    }

    u16* ob = O + (size_t)(b * S + q0 + lg * 4) * H + h * HD;
    #pragma unroll
    for (int r = 0; r < 4; ++r) {
      float inv = 1.f / lrun[r];
      #pragma unroll
      for (int fd = 0; fd < 8; ++fd)
        ob[(size_t)r * H + fd * 16 + lr] = f2bf(acc[fd][r] * inv);
    }
  }
}

// ---------------- launch ----------------
extern "C" void kernel_launch(void* const* d_in, const int* in_sizes, int n_in,
                              void* d_out, int out_size, void* d_ws, size_t ws_size,
                              hipStream_t stream) {
  const float* x  = (const float*)d_in[0];
  const float* wq = (const float*)d_in[1];
  const float* bq = (const float*)d_in[2];
  const float* wk = (const float*)d_in[3];
  const float* bk = (const float*)d_in[4];
  const float* wv = (const float*)d_in[5];
  const float* bv = (const float*)d_in[6];
  const float* wo = (const float*)d_in[7];
  const float* bo = (const float*)d_in[8];

  char* ws = (char*)d_ws;
  u16*   xb  = (u16*)(ws);                       // 16 MiB  [M][H] bf16
  u16*   wqb = (u16*)(ws + (16ull << 20));       //  8 MiB
  u16*   wkb = (u16*)(ws + (24ull << 20));
  u16*   wvb = (u16*)(ws + (32ull << 20));
  u16*   wob = (u16*)(ws + (40ull << 20));
  u16*   Qb  = (u16*)(ws + (48ull << 20));       // 16 MiB
  u16*   Kb  = (u16*)(ws + (64ull << 20));       // 16 MiB
  u16*   Vt  = (u16*)(ws + (80ull << 20));       // 16 MiB [bh][d][s]
  u16*   Ob  = (u16*)(ws + (96ull << 20));       // 16 MiB
  float* tab = (float*)(ws + (112ull << 20));    //  1 MiB cos/sin

  cast_kernel<<<M * H / 1024, 256, 0, stream>>>(x, xb, M * H);
  cast4_kernel<<<dim3(H * H / 1024, 4), 256, 0, stream>>>(wq, wk, wv, wo, wqb, wkb, wvb, wob);
  rope_table_k<<<(S * 64 + 255) / 256, 256, 0, stream>>>(tab);

  gemm8_qkv<<<384, 512, 0, stream>>>(xb, wqb, wkb, wvb, bq, bk, bv, Qb, Kb, Vt);

  rope_apply2_k<<<dim3(M * NH * 8 / 256, 2), 256, 0, stream>>>(Qb, Kb, tab);

  attn_fwd<<<512, 256, 0, stream>>>(Qb, Kb, Vt, Ob);

  gemm8_out<<<128, 512, 0, stream>>>(Ob, wob, bo, (float*)d_out);
}

// Round 5
// 275.528 us; speedup vs baseline: 1.1916x; 1.1916x over previous
//
#include <hip/hip_runtime.h>

typedef unsigned short u16;
typedef __attribute__((ext_vector_type(8))) __bf16 bf16x8;
typedef __attribute__((ext_vector_type(4))) float f32x4;
typedef __attribute__((ext_vector_type(4))) u16 u16x4;
typedef __attribute__((ext_vector_type(8))) u16 u16x8;

constexpr int S = 2048;
constexpr int H = 2048;
constexpr int NH = 16;
constexpr int HD = 128;
constexpr int M = 4096;   // B*S
constexpr float SCALE = 0.08838834764831845f;  // 1/sqrt(128)

__device__ __forceinline__ u16 f2bf(float f) {
  union { float f; unsigned u; } v; v.f = f;
  unsigned r = v.u + 0x7fffu + ((v.u >> 16) & 1u);  // RNE
  return (u16)(r >> 16);
}
__device__ __forceinline__ float bf2f(u16 u) {
  union { unsigned u; float f; } v; v.u = ((unsigned)u) << 16;
  return v.f;
}
__device__ __forceinline__ unsigned cvt_pk_bf16(float lo, float hi) {
  unsigned r;
  asm("v_cvt_pk_bf16_f32 %0, %1, %2" : "=v"(r) : "v"(lo), "v"(hi));
  return r;
}
__device__ __forceinline__ f32x4 MFMA16(bf16x8 a, bf16x8 b, f32x4 c) {
  return __builtin_amdgcn_mfma_f32_16x16x32_bf16(a, b, c, 0, 0, 0);
}

// async global->LDS, 16 bytes per lane. LDS dest must be wave-uniform base + lane*16.
__device__ __forceinline__ void gld16(const u16* g, u16* l) {
  __builtin_amdgcn_global_load_lds(
      (const __attribute__((address_space(1))) void*)g,
      (__attribute__((address_space(3))) void*)l, 16, 0, 0);
}

#define SBAR  { __builtin_amdgcn_sched_barrier(0); __builtin_amdgcn_s_barrier(); __builtin_amdgcn_sched_barrier(0); }
#define LGKM0 { asm volatile("s_waitcnt lgkmcnt(0)" ::: "memory"); __builtin_amdgcn_sched_barrier(0); }

// ---------------- fp32 -> bf16 cast (x) ----------------
__global__ __launch_bounds__(256) void cast_kernel(const float* __restrict__ in,
                                                   u16* __restrict__ out, int n) {
  int i = (blockIdx.x * 256 + threadIdx.x) * 4;
  if (i >= n) return;
  float4 v = *(const float4*)(in + i);
  u16x4 o;
  o[0] = f2bf(v.x); o[1] = f2bf(v.y); o[2] = f2bf(v.z); o[3] = f2bf(v.w);
  *(u16x4*)(out + i) = o;
}

// ---------------- 4 weight casts in one dispatch ----------------
__global__ __launch_bounds__(256) void cast4_kernel(const float* __restrict__ i0,
                                                    const float* __restrict__ i1,
                                                    const float* __restrict__ i2,
                                                    const float* __restrict__ i3,
                                                    u16* o0, u16* o1, u16* o2, u16* o3) {
  const float* in; u16* out;
  switch (blockIdx.y) {
    case 0: in = i0; out = o0; break;
    case 1: in = i1; out = o1; break;
    case 2: in = i2; out = o2; break;
    default: in = i3; out = o3; break;
  }
  int i = (blockIdx.x * 256 + threadIdx.x) * 4;
  float4 v = *(const float4*)(in + i);
  u16x4 o;
  o[0] = f2bf(v.x); o[1] = f2bf(v.y); o[2] = f2bf(v.z); o[3] = f2bf(v.w);
  *(u16x4*)(out + i) = o;
}

// ---------------- concat biases into [6144] ----------------
__global__ __launch_bounds__(256) void concat_bias_k(const float* __restrict__ bq,
                                                     const float* __restrict__ bk,
                                                     const float* __restrict__ bv,
                                                     float* __restrict__ bqkv) {
  int i = blockIdx.x * 256 + threadIdx.x;  // 0..6143
  const float* src = (i < 2048) ? bq : (i < 4096) ? bk : bv;
  bqkv[i] = src[i & 2047];
}

// ---------------- RoPE cos/sin table ----------------
__global__ __launch_bounds__(256) void rope_table_k(float* __restrict__ tab) {
  int i = blockIdx.x * 256 + threadIdx.x;
  if (i >= S * 64) return;
  int s = i >> 6, d = i & 63;
  float freq = expf(-(float)d * (9.210340371976184f / 64.f));  // 10000^(-d/64)
  float ang = (float)s * freq;
  tab[i * 2]     = cosf(ang);
  tab[i * 2 + 1] = sinf(ang);
}

// ---------------- RoPE apply to Q (pre-scaled) and K, one dispatch ----------------
__global__ __launch_bounds__(256) void rope_apply2_k(u16* __restrict__ Qb, u16* __restrict__ Kb,
                                                     const float* __restrict__ tab) {
  u16* X = blockIdx.y ? Kb : Qb;
  const float sc = blockIdx.y ? 1.f : SCALE;
  int i = blockIdx.x * 256 + threadIdx.x;
  int j0 = (i & 7) * 8;
  int h  = (i >> 3) & 15;
  int m  = i >> 7;
  int s  = m & (S - 1);
  u16* p = X + (size_t)m * H + h * HD;
  u16x8 lo = *(u16x8*)(p + j0);
  u16x8 hi = *(u16x8*)(p + 64 + j0);
  u16x8 nlo, nhi;
  const float* tb = tab + ((size_t)s * 64 + j0) * 2;
  #pragma unroll
  for (int j = 0; j < 8; ++j) {
    float c = tb[j * 2], sn = tb[j * 2 + 1];
    float xl = bf2f(lo[j]), xh = bf2f(hi[j]);
    nlo[j] = f2bf((xl * c - xh * sn) * sc);
    nhi[j] = f2bf((xh * c + xl * sn) * sc);
  }
  *(u16x8*)(p + j0) = nlo;
  *(u16x8*)(p + 64 + j0) = nhi;
}

// ================= 256(M) x NW*64(N) 8-phase GEMM =================
// C[m,n] = sum_k A[m,k]*W[n,k] + bias[n]; K=2048, BK=64 (32 K-tiles, 16 iters x 2).
// 8 waves (2M x 4N), per-wave 128 x NW*16. LDS: A 2x[256][64], B 2x[NW*64][64].
// Chunk-XOR swizzle (source-swizzled stage, same involution on ds_read) -> 0 conflicts.
// Per K-tile (4 phases): reads 7/4/7/4 (no reloads); MFMA 4m x NW x 1k per phase.
// Stage ledger (ops: A-half=2 loads, B=NW loads):
//   ph1: A1h0<-u+1  ph2: A1h1<-u+1  ph4: B0<-u+2 + GATE vmcnt(NW)
//   ph5: A0h0<-u+2  ph6: A0h1<-u+2  ph8: B1<-u+3 + GATE vmcnt(NW)
// Each gate retires exactly the next tile's 3 ops (issued 2-6 phases earlier).
// EMODE 0: fp32 out. EMODE 3: fused QKV (col>>11 selects Q/K linear or V-transposed).
template<int NW, int EMODE>
__device__ __forceinline__ void gemm_body(const u16* __restrict__ A,
                                          const u16* __restrict__ Bw,
                                          const float* __restrict__ bias,
                                          void* __restrict__ out0, void* __restrict__ out1,
                                          void* __restrict__ out2,
                                          int brow, int bcol,
                                          u16* AsL, u16* BsL) {
  const int t = threadIdx.x;
  const int w = t >> 6, l = t & 63;
  const int wr = w >> 2, wc = w & 3;
  const int lr = l & 15, lg = l >> 4;
  const int swz = lr & 7;

  f32x4 acc[8][NW] = {};
  bf16x8 af[4], b0[NW], b1[NW];

  const int sr = t >> 3, sj = t & 7;   // stage row (0..63) / chunk (0..7)

  auto STAGE_A = [&](int BUF, int HALF, int TILE) {
    u16* d = AsL + BUF * (256 * 64) + HALF * (128 * 64);
    const u16* sp = A + (size_t)(brow + HALF * 128) * H + TILE * 64;
    gld16(sp + (size_t)sr * H        + ((sj ^ (sr & 7)) * 8), d + t * 8);
    gld16(sp + (size_t)(64 + sr) * H + ((sj ^ (sr & 7)) * 8), d + (512 + t) * 8);
  };
  auto STAGE_B = [&](int BUF, int TILE) {
    u16* d = BsL + BUF * (NW * 64 * 64);
    const u16* sp = Bw + (size_t)bcol * H + TILE * 64;
    #pragma unroll
    for (int i = 0; i < NW; ++i)
      gld16(sp + (size_t)(i * 64 + sr) * H + ((sj ^ (sr & 7)) * 8),
            d + (i * 512 + t) * 8);
  };
  auto LDA = [&](int BUF, int KH, int MB) {
    const u16* base = AsL + BUF * (256 * 64) + (wr * 128 + MB * 16 + lr) * 64;
    #pragma unroll
    for (int i = 0; i < 4; ++i)
      af[i] = *(const bf16x8*)(base + i * (16 * 64) + (((KH * 4 + lg) ^ swz) * 8));
  };
  auto LDB = [&](int BUF, int KH, bf16x8* bb) {
    const u16* base = BsL + BUF * (NW * 64 * 64) + (wc * (NW * 16) + lr) * 64;
    #pragma unroll
    for (int n = 0; n < NW; ++n)
      bb[n] = *(const bf16x8*)(base + n * (16 * 64) + (((KH * 4 + lg) ^ swz) * 8));
  };
  auto MM = [&](int MB, bf16x8* bb) {
    __builtin_amdgcn_s_setprio(1);
    #pragma unroll
    for (int i = 0; i < 4; ++i)
      #pragma unroll
      for (int n = 0; n < NW; ++n)
        acc[MB + i][n] = MFMA16(af[i], bb[n], acc[MB + i][n]);
    __builtin_amdgcn_s_setprio(0);
  };
  auto GATE = [&]() {
    if constexpr (NW == 3) { asm volatile("s_waitcnt vmcnt(3)" ::: "memory"); }
    else                   { asm volatile("s_waitcnt vmcnt(2)" ::: "memory"); }
  };

  // prologue: A0<-t0, B0<-t0, B1<-t1; retire all but B1
  STAGE_A(0, 0, 0); STAGE_A(0, 1, 0);
  STAGE_B(0, 0);
  STAGE_B(1, 1);
  GATE();
  SBAR;

  for (int J = 0; J < 16; ++J) {
    const int u = 2 * J;
    const bool more = (J < 15);
    // ---- tile u (buf0) ----
    // ph1
    LDA(0, 0, 0); LDB(0, 0, b0);
    STAGE_A(1, 0, u + 1);
    SBAR; LGKM0; MM(0, b0); SBAR;
    // ph2
    LDA(0, 0, 4);
    STAGE_A(1, 1, u + 1);
    SBAR; LGKM0; MM(4, b0); SBAR;
    // ph3
    LDA(0, 1, 0); LDB(0, 1, b1);
    SBAR; LGKM0; MM(0, b1); SBAR;
    // ph4 (gate: tile u+1 A,B complete)
    LDA(0, 1, 4);
    if (more) STAGE_B(0, u + 2);
    SBAR; LGKM0; MM(4, b1);
    if (more) { GATE(); } else { asm volatile("s_waitcnt vmcnt(0)" ::: "memory"); }
    SBAR;
    // ---- tile u+1 (buf1) ----
    // ph5
    LDA(1, 0, 0); LDB(1, 0, b0);
    if (more) STAGE_A(0, 0, u + 2);
    SBAR; LGKM0; MM(0, b0); SBAR;
    // ph6
    LDA(1, 0, 4);
    if (more) STAGE_A(0, 1, u + 2);
    SBAR; LGKM0; MM(4, b0); SBAR;
    // ph7
    LDA(1, 1, 0); LDB(1, 1, b1);
    SBAR; LGKM0; MM(0, b1); SBAR;
    // ph8 (gate: tile u+2 A,B complete)
    LDA(1, 1, 4);
    if (more) STAGE_B(1, u + 3);
    SBAR; LGKM0; MM(4, b1);
    if (more) { GATE(); SBAR; }
  }

  // ---- epilogue ----
  #pragma unroll
  for (int m = 0; m < 8; ++m) {
    const int row0 = brow + wr * 128 + m * 16 + lg * 4;
    #pragma unroll
    for (int n = 0; n < NW; ++n) {
      const int gcol0 = bcol + wc * (NW * 16) + n * 16;
      const float bv = bias[gcol0 + lr];
      if constexpr (EMODE == 0) {
        float* C = (float*)out0;
        #pragma unroll
        for (int r = 0; r < 4; ++r)
          C[(size_t)(row0 + r) * H + gcol0 + lr] = acc[m][n][r] + bv;
      } else {
        const int sel = gcol0 >> 11;           // wave-uniform (16-col frag never crosses 2048)
        const int col = (gcol0 & 2047) + lr;
        if (sel < 2) {
          u16* C = sel ? (u16*)out1 : (u16*)out0;
          #pragma unroll
          for (int r = 0; r < 4; ++r)
            C[(size_t)(row0 + r) * H + col] = f2bf(acc[m][n][r] + bv);
        } else {
          // V transposed: Vt[((b*16+h)*128+d)*S + s]
          const int hh = col >> 7, d = col & 127;
          const int b = row0 >> 11, s0 = row0 & (S - 1);
          u16x4 pk;
          #pragma unroll
          for (int r = 0; r < 4; ++r) pk[r] = f2bf(acc[m][n][r] + bv);
          *(u16x4*)((u16*)out2 + ((size_t)((b * 16 + hh) * 128 + d)) * S + s0) = pk;
        }
      }
    }
  }
}

// fused QKV: M=4096 x N=6144, 256x192 tiles -> 16x32 = 512 blocks (2 exact rounds).
// XCD stripe: each XCD owns a 16M x 4N column stripe (B-stripe 3 MB -> L2-resident).
__global__ __launch_bounds__(512, 2) void gemm_qkv8(const u16* __restrict__ xb,
                                                    const u16* __restrict__ wqkv,
                                                    const float* __restrict__ bqkv,
                                                    u16* Qb, u16* Kb, u16* Vt) {
  __shared__ u16 AsL[2 * 256 * 64];   // 64 KiB
  __shared__ u16 BsL[2 * 192 * 64];   // 48 KiB
  const int id = blockIdx.x;
  const int xcd = id & 7, sid = id >> 3;
  const int bx = xcd * 4 + (sid & 3), by = sid >> 2;
  gemm_body<3, 3>(xb, wqkv, bqkv, Qb, Kb, Vt, by * 256, bx * 192, AsL, BsL);
}

// out-proj: M=4096 x N=2048, 256x128 tiles -> 16x16 = 256 blocks (1 exact round).
__global__ __launch_bounds__(512, 2) void gemm_o8(const u16* __restrict__ A,
                                                  const u16* __restrict__ W,
                                                  const float* __restrict__ bias,
                                                  float* __restrict__ C) {
  __shared__ u16 AsL[2 * 256 * 64];   // 64 KiB
  __shared__ u16 BsL[2 * 128 * 64];   // 32 KiB
  const int id = blockIdx.x;
  const int xcd = id & 7, sid = id >> 3;
  const int bx = xcd * 2 + (sid & 1), by = sid >> 1;
  gemm_body<2, 0>(A, W, bias, C, nullptr, nullptr, by * 256, bx * 128, AsL, BsL);
}

// ---------------- causal flash attention (unchanged from R3) ----------------
__global__ __launch_bounds__(256) void attn_fwd(const u16* __restrict__ Q,
                                                const u16* __restrict__ Kx,
                                                const u16* __restrict__ Vt,
                                                u16* __restrict__ O) {
  const int id = blockIdx.x;
  const int xcd = id & 7, slot = id >> 3;
  const int bh = (slot >> 4) * 8 + xcd;    // 0..31
  const int pid = slot & 15;               // 0..15
  const int b = bh >> 4, h = bh & 15;
  const int t = threadIdx.x, w = t >> 6, l = t & 63;
  const int lr = l & 15, lg = l >> 4;
  const int swz = lr & 7;

  __shared__ u16 Ks[2][64 * 128];
  __shared__ u16 Vs[2][128 * 64];
  __shared__ u16 P_lds[4][16 * 64];
  u16* pw = &P_lds[w][0];

  const u16* kbase = Kx + (size_t)(b * S) * H + h * HD;
  const u16* vbase = Vt + (size_t)bh * HD * S;

  auto stageK = [&](int bf, int k0) {
    #pragma unroll
    for (int it = 0; it < 4; ++it) {
      int c = it * 256 + t;
      int row = c >> 4, j = c & 15;
      gld16(kbase + (size_t)(k0 + row) * H + ((j ^ (row & 7)) * 8), &Ks[bf][0] + c * 8);
    }
  };
  auto stageV = [&](int bf, int k0) {
    #pragma unroll
    for (int it = 0; it < 4; ++it) {
      int c = it * 256 + t;
      int row = c >> 3, j = c & 7;
      gld16(vbase + (size_t)row * S + k0 + ((j ^ (row & 7)) * 8), &Vs[bf][0] + c * 8);
    }
  };

  int cur = 0;
  for (int qi = 0; qi < 2; ++qi) {
    const int qt = qi ? pid : (31 - pid);
    const int q0 = qt * 64 + w * 16;

    bf16x8 qa[4];
    const u16* qbase = Q + (size_t)(b * S + q0 + lr) * H + h * HD;
    #pragma unroll
    for (int ks = 0; ks < 4; ++ks)
      qa[ks] = *(const bf16x8*)(qbase + ks * 32 + lg * 8);

    f32x4 acc[8] = {};
    float mrun[4], lrun[4];
    #pragma unroll
    for (int r = 0; r < 4; ++r) { mrun[r] = -1e30f; lrun[r] = 0.f; }

    __syncthreads();
    stageK(cur, 0);
    stageV(cur, 0);
    __syncthreads();

    for (int kt = 0; kt <= qt; ++kt) {
      if (kt < qt) {
        stageK(cur ^ 1, (kt + 1) * 64);
        stageV(cur ^ 1, (kt + 1) * 64);
      }
      const u16* kl = &Ks[cur][0];
      const u16* vl = &Vs[cur][0];

      f32x4 sc[4] = {};
      __builtin_amdgcn_s_setprio(1);
      #pragma unroll
      for (int ks = 0; ks < 4; ++ks) {
        #pragma unroll
        for (int f = 0; f < 4; ++f) {
          bf16x8 kf = *(const bf16x8*)(kl + (f * 16 + lr) * 128 + (((ks * 4 + lg) ^ swz) * 8));
          sc[f] = __builtin_amdgcn_mfma_f32_16x16x32_bf16(qa[ks], kf, sc[f], 0, 0, 0);
        }
      }
      __builtin_amdgcn_s_setprio(0);
      const bool diag = (kt == qt);
      float p[4][4];
      #pragma unroll
      for (int f = 0; f < 4; ++f)
        #pragma unroll
        for (int r = 0; r < 4; ++r) {
          float v = sc[f][r];
          if (diag && (f * 16 + lr > w * 16 + lg * 4 + r)) v = -1e30f;
          p[f][r] = v;
        }
      float mx[4];
      #pragma unroll
      for (int r = 0; r < 4; ++r) {
        float m0 = fmaxf(fmaxf(p[0][r], p[1][r]), fmaxf(p[2][r], p[3][r]));
        m0 = fmaxf(m0, __shfl_xor(m0, 1));
        m0 = fmaxf(m0, __shfl_xor(m0, 2));
        m0 = fmaxf(m0, __shfl_xor(m0, 4));
        m0 = fmaxf(m0, __shfl_xor(m0, 8));
        mx[r] = m0;
      }
      bool grow = (mx[0] > mrun[0] + 8.f) || (mx[1] > mrun[1] + 8.f) ||
                  (mx[2] > mrun[2] + 8.f) || (mx[3] > mrun[3] + 8.f);
      if (__any(grow)) {
        float resc[4];
        #pragma unroll
        for (int r = 0; r < 4; ++r) {
          float mnew = fmaxf(mrun[r], mx[r]);
          resc[r] = __expf(mrun[r] - mnew);
          mrun[r] = mnew;
          lrun[r] *= resc[r];
        }
        #pragma unroll
        for (int fd = 0; fd < 8; ++fd) {
          f32x4 a = acc[fd];
          a[0] *= resc[0]; a[1] *= resc[1]; a[2] *= resc[2]; a[3] *= resc[3];
          acc[fd] = a;
        }
      }
      #pragma unroll
      for (int r = 0; r < 4; ++r) {
        float sum = 0.f;
        #pragma unroll
        for (int f = 0; f < 4; ++f) {
          float e = __expf(p[f][r] - mrun[r]);
          p[f][r] = e;
          sum += e;
        }
        sum += __shfl_xor(sum, 1);
        sum += __shfl_xor(sum, 2);
        sum += __shfl_xor(sum, 4);
        sum += __shfl_xor(sum, 8);
        lrun[r] += sum;
      }
      {
        const int r0 = lg * 4;
        #pragma unroll
        for (int f = 0; f < 4; ++f) {
          const int col = f * 16 + lr;
          unsigned w01 = cvt_pk_bf16(p[f][0], p[f][1]);
          unsigned w23 = cvt_pk_bf16(p[f][2], p[f][3]);
          pw[(r0 + 0) * 64 + (col ^ (((r0 + 0) & 7) << 3))] = (u16)(w01 & 0xffffu);
          pw[(r0 + 1) * 64 + (col ^ (((r0 + 1) & 7) << 3))] = (u16)(w01 >> 16);
          pw[(r0 + 2) * 64 + (col ^ (((r0 + 2) & 7) << 3))] = (u16)(w23 & 0xffffu);
          pw[(r0 + 3) * 64 + (col ^ (((r0 + 3) & 7) << 3))] = (u16)(w23 >> 16);
        }
      }
      __builtin_amdgcn_s_setprio(1);
      #pragma unroll
      for (int ks = 0; ks < 2; ++ks) {
        int col0 = ks * 32 + lg * 8;
        bf16x8 pa = *(const bf16x8*)(pw + lr * 64 + (col0 ^ (swz << 3)));
        #pragma unroll
        for (int fd = 0; fd < 8; ++fd) {
          bf16x8 vb = *(const bf16x8*)(vl + (fd * 16 + lr) * 64 + (((ks * 4 + lg) ^ swz) * 8));
          acc[fd] = __builtin_amdgcn_mfma_f32_16x16x32_bf16(pa, vb, acc[fd], 0, 0, 0);
        }
      }
      __builtin_amdgcn_s_setprio(0);
      __syncthreads();
      cur ^= 1;
    }

    u16* ob = O + (size_t)(b * S + q0 + lg * 4) * H + h * HD;
    #pragma unroll
    for (int r = 0; r < 4; ++r) {
      float inv = 1.f / lrun[r];
      #pragma unroll
      for (int fd = 0; fd < 8; ++fd)
        ob[(size_t)r * H + fd * 16 + lr] = f2bf(acc[fd][r] * inv);
    }
  }
}

// ---------------- launch ----------------
extern "C" void kernel_launch(void* const* d_in, const int* in_sizes, int n_in,
                              void* d_out, int out_size, void* d_ws, size_t ws_size,
                              hipStream_t stream) {
  const float* x  = (const float*)d_in[0];
  const float* wq = (const float*)d_in[1];
  const float* bq = (const float*)d_in[2];
  const float* wk = (const float*)d_in[3];
  const float* bk = (const float*)d_in[4];
  const float* wv = (const float*)d_in[5];
  const float* bv = (const float*)d_in[6];
  const float* wo = (const float*)d_in[7];
  const float* bo = (const float*)d_in[8];

  char* ws = (char*)d_ws;
  u16*   xb    = (u16*)(ws);                      // 16 MiB  [M][H] bf16
  u16*   wqkvb = (u16*)(ws + (16ull << 20));      // 24 MiB  [6144][2048] (Wq|Wk|Wv)
  u16*   wob   = (u16*)(ws + (40ull << 20));      //  8 MiB
  u16*   Qb    = (u16*)(ws + (48ull << 20));      // 16 MiB
  u16*   Kb    = (u16*)(ws + (64ull << 20));      // 16 MiB
  u16*   Vt    = (u16*)(ws + (80ull << 20));      // 16 MiB [bh][d][s]
  u16*   Ob    = (u16*)(ws + (96ull << 20));      // 16 MiB
  float* tab   = (float*)(ws + (112ull << 20));   //  1 MiB cos/sin
  float* bqkv  = (float*)(ws + (113ull << 20));   // 24 KiB [6144]

  cast_kernel<<<M * H / 1024, 256, 0, stream>>>(x, xb, M * H);
  cast4_kernel<<<dim3(H * H / 1024, 4), 256, 0, stream>>>(
      wq, wk, wv, wo, wqkvb, wqkvb + (size_t)H * H, wqkvb + 2ull * H * H, wob);
  rope_table_k<<<(S * 64 + 255) / 256, 256, 0, stream>>>(tab);
  concat_bias_k<<<24, 256, 0, stream>>>(bq, bk, bv, bqkv);

  gemm_qkv8<<<512, 512, 0, stream>>>(xb, wqkvb, bqkv, Qb, Kb, Vt);

  rope_apply2_k<<<dim3(M * NH * 8 / 256, 2), 256, 0, stream>>>(Qb, Kb, tab);

  attn_fwd<<<512, 256, 0, stream>>>(Qb, Kb, Vt, Ob);

  gemm_o8<<<256, 512, 0, stream>>>(Ob, wob, bo, (float*)d_out);
}